// Round 1
// baseline (526.811 us; speedup 1.0000x reference)
//
#include <hip/hip_runtime.h>
#include <math.h>

#define NEG_INF (-3.402823466e38f)

// ===================== CSR build =====================
__global__ void k_count(const int* __restrict__ edges, int* __restrict__ cnt, int E) {
  int e = blockIdx.x * 256 + threadIdx.x;
  if (e < E) atomicAdd(&cnt[edges[E + e]], 1);
}

__global__ void k_dinv(const int* __restrict__ cnt, float* __restrict__ dinv, int n) {
  int i = blockIdx.x * 256 + threadIdx.x;
  if (i < n) dinv[i] = rsqrtf((float)cnt[i] + 1.0f);  // +1 = self loop
}

__global__ void k_scan1(const int* __restrict__ cnt, int* __restrict__ incl,
                        int* __restrict__ bsum, int n) {
  __shared__ int s[256];
  int tid = threadIdx.x;
  int gid = blockIdx.x * 256 + tid;
  int x = (gid < n) ? cnt[gid] : 0;
  s[tid] = x;
  __syncthreads();
  #pragma unroll
  for (int off = 1; off < 256; off <<= 1) {
    int t = (tid >= off) ? s[tid - off] : 0;
    __syncthreads();
    x += t; s[tid] = x;
    __syncthreads();
  }
  incl[gid] = x;
  if (tid == 255) bsum[blockIdx.x] = x;
}

__global__ void k_scan2(int* __restrict__ bsum, int nb) {
  __shared__ int s[256];
  int tid = threadIdx.x;
  int x = (tid < nb) ? bsum[tid] : 0;
  s[tid] = x;
  __syncthreads();
  #pragma unroll
  for (int off = 1; off < 256; off <<= 1) {
    int t = (tid >= off) ? s[tid - off] : 0;
    __syncthreads();
    x += t; s[tid] = x;
    __syncthreads();
  }
  if (tid < nb) bsum[tid] = x;
}

__global__ void k_scan3(const int* __restrict__ incl, const int* __restrict__ cnt,
                        const int* __restrict__ bsum, int* __restrict__ offs,
                        int* __restrict__ curs, int n, int E) {
  int gid = blockIdx.x * 256 + threadIdx.x;
  if (gid < n) {
    int base = (blockIdx.x > 0) ? bsum[blockIdx.x - 1] : 0;
    int v = incl[gid] - cnt[gid] + base;   // exclusive
    offs[gid] = v;
    curs[gid] = v;
  }
  if (gid == 0) offs[n] = E;
}

__global__ void k_fill(const int* __restrict__ edges, int* __restrict__ curs,
                       int* __restrict__ csr, int E) {
  int e = blockIdx.x * 256 + threadIdx.x;
  if (e < E) {
    int s = edges[e];
    int d = edges[E + e];
    int pos = atomicAdd(&curs[d], 1);
    csr[pos] = s;
  }
}

// ===================== dense GEMM: T = (A @ W) * dinv[row] =====================
// A [n,128], W [128,128] row-major. Block: 256 thr, 64 rows x 128 cols.
__global__ __launch_bounds__(256) void k_gemm(
    const float* __restrict__ A, const float* __restrict__ W,
    const float* __restrict__ dinv, float* __restrict__ T, int n)
{
  __shared__ float sW[128 * 128];   // 64 KB
  __shared__ float sX[128 * 64];    // 32 KB, transposed: (k,r) at k*64 + (r ^ swz(k))
  int tid = threadIdx.x;
  int rbase = blockIdx.x * 64;

  {
    const float4* W4 = (const float4*)W;
    float4* sW4 = (float4*)sW;
    #pragma unroll
    for (int i = 0; i < 16; ++i) sW4[i * 256 + tid] = W4[i * 256 + tid];
  }
  {
    int k4 = tid & 31;        // float4 index within a row: k = 4*k4+j
    int r0 = tid >> 5;        // 0..7
    int swz = (k4 & 7) << 2;  // ((k>>2)&7)<<2
    #pragma unroll
    for (int l = 0; l < 8; ++l) {
      int r = r0 + (l << 3);
      int row = rbase + r;
      float4 v = make_float4(0.f, 0.f, 0.f, 0.f);
      if (row < n) v = *(const float4*)(A + (size_t)row * 128 + (k4 << 2));
      int rs = r ^ swz;
      sX[(k4 * 4 + 0) * 64 + rs] = v.x;
      sX[(k4 * 4 + 1) * 64 + rs] = v.y;
      sX[(k4 * 4 + 2) * 64 + rs] = v.z;
      sX[(k4 * 4 + 3) * 64 + rs] = v.w;
    }
  }
  __syncthreads();

  int cg = tid & 15;   // cols cg*8 .. cg*8+7
  int rg = tid >> 4;   // rows rg*4 .. rg*4+3
  float acc[4][8];
  #pragma unroll
  for (int i = 0; i < 4; ++i)
    #pragma unroll
    for (int j = 0; j < 8; ++j) acc[i][j] = 0.f;

  #pragma unroll 4
  for (int k = 0; k < 128; ++k) {
    int swz = ((k >> 2) & 7) << 2;
    float4 xv = *(const float4*)(sX + k * 64 + ((rg << 2) ^ swz));
    float4 wa = *(const float4*)(sW + k * 128 + (cg << 3));
    float4 wb = *(const float4*)(sW + k * 128 + (cg << 3) + 4);
    float xr[4] = {xv.x, xv.y, xv.z, xv.w};
    float wr[8] = {wa.x, wa.y, wa.z, wa.w, wb.x, wb.y, wb.z, wb.w};
    #pragma unroll
    for (int i = 0; i < 4; ++i)
      #pragma unroll
      for (int j = 0; j < 8; ++j)
        acc[i][j] = fmaf(xr[i], wr[j], acc[i][j]);
  }

  #pragma unroll
  for (int i = 0; i < 4; ++i) {
    int row = rbase + (rg << 2) + i;
    if (row < n) {
      float s = dinv[row];
      float4 o0 = make_float4(acc[i][0]*s, acc[i][1]*s, acc[i][2]*s, acc[i][3]*s);
      float4 o1 = make_float4(acc[i][4]*s, acc[i][5]*s, acc[i][6]*s, acc[i][7]*s);
      float* dst = T + (size_t)row * 128 + (cg << 3);
      *(float4*)dst = o0;
      *(float4*)(dst + 4) = o1;
    }
  }
}

// ===================== sparse aggregate =====================
// H[u] = relu?( dinv[u] * (T'[u] + sum_{e in CSR[u]} T'[src_e]) + b )
// T' rows already scaled by dinv[src]. 128 threads per node, 2 nodes/block.
__global__ __launch_bounds__(256) void k_agg(
    const float* __restrict__ T, const int* __restrict__ offs,
    const int* __restrict__ csr, const float* __restrict__ dinv,
    const float* __restrict__ bias, float* __restrict__ H, int n, int relu)
{
  int u = blockIdx.x * 2 + (threadIdx.x >> 7);
  int c = threadIdx.x & 127;
  if (u >= n) return;
  float acc = T[(size_t)u * 128 + c];   // self loop
  int e0 = offs[u], e1 = offs[u + 1];
  int e = e0;
  for (; e + 3 < e1; e += 4) {
    int s0 = csr[e], s1 = csr[e + 1], s2 = csr[e + 2], s3 = csr[e + 3];
    float v0 = T[(size_t)s0 * 128 + c];
    float v1 = T[(size_t)s1 * 128 + c];
    float v2 = T[(size_t)s2 * 128 + c];
    float v3 = T[(size_t)s3 * 128 + c];
    acc += (v0 + v1) + (v2 + v3);
  }
  for (; e < e1; ++e) acc += T[(size_t)csr[e] * 128 + c];
  float v = fmaf(acc, dinv[u], bias[c]);
  if (relu) v = fmaxf(v, 0.f);
  H[(size_t)u * 128 + c] = v;
}

// ===================== head: logits + log_softmax =====================
// One wave per row; lane = class (40 used, 24 idle). W_out column cached in VGPRs.
__global__ __launch_bounds__(256) void k_head(
    const float* __restrict__ H, const float* __restrict__ Wo,
    const float* __restrict__ bo, float* __restrict__ out, int n, int nwaves)
{
  int lane = threadIdx.x & 63;
  int wid = (blockIdx.x << 2) + (threadIdx.x >> 6);
  int cc = (lane < 40) ? lane : 0;
  float wreg[128];
  #pragma unroll
  for (int k = 0; k < 128; ++k) wreg[k] = Wo[k * 40 + cc];
  float bv = bo[cc];

  for (int r = wid; r < n; r += nwaves) {
    const float* hr = H + (size_t)r * 128;
    float a0 = 0.f, a1 = 0.f, a2 = 0.f, a3 = 0.f;
    #pragma unroll
    for (int k = 0; k < 128; k += 4) {
      a0 = fmaf(hr[k],     wreg[k],     a0);
      a1 = fmaf(hr[k + 1], wreg[k + 1], a1);
      a2 = fmaf(hr[k + 2], wreg[k + 2], a2);
      a3 = fmaf(hr[k + 3], wreg[k + 3], a3);
    }
    float logit = (a0 + a1) + (a2 + a3) + bv;
    float m = (lane < 40) ? logit : NEG_INF;
    #pragma unroll
    for (int o = 32; o; o >>= 1) m = fmaxf(m, __shfl_xor(m, o));
    float ex = (lane < 40) ? __expf(logit - m) : 0.f;
    float s = ex;
    #pragma unroll
    for (int o = 32; o; o >>= 1) s += __shfl_xor(s, o);
    if (lane < 40) out[(size_t)r * 40 + lane] = logit - m - __logf(s);
  }
}

// ===================== launch =====================
extern "C" void kernel_launch(void* const* d_in, const int* in_sizes, int n_in,
                              void* d_out, int out_size, void* d_ws, size_t ws_size,
                              hipStream_t stream) {
  const float* x    = (const float*)d_in[0];
  const int*   edges= (const int*)d_in[1];
  const float* W_in = (const float*)d_in[2];
  const float* b_in = (const float*)d_in[3];
  const float* W1   = (const float*)d_in[4];
  const float* b1   = (const float*)d_in[5];
  const float* W2   = (const float*)d_in[6];
  const float* b2   = (const float*)d_in[7];
  const float* Wo   = (const float*)d_in[8];
  const float* bo   = (const float*)d_in[9];
  float* out = (float*)d_out;

  int N = in_sizes[0] / 128;
  int E = in_sizes[1] / 2;
  int NB = (N + 255) / 256;
  int EB = (E + 255) / 256;

  char* p = (char*)d_ws;
  auto alloc = [&](size_t bytes) {
    char* r = p; p += (bytes + 255) & ~(size_t)255; return r;
  };
  float* t    = (float*)alloc((size_t)N * 128 * 4);
  float* h    = (float*)alloc((size_t)N * 128 * 4);
  int*   cnt  = (int*)  alloc((size_t)N * 4);
  float* dinv = (float*)alloc((size_t)N * 4);
  int*   incl = (int*)  alloc((size_t)NB * 256 * 4);
  int*   bsum = (int*)  alloc(256 * 4);
  int*   offs = (int*)  alloc((size_t)(N + 1) * 4);
  int*   curs = (int*)  alloc((size_t)N * 4);
  int*   csr  = (int*)  alloc((size_t)E * 4);
  (void)ws_size; (void)n_in; (void)out_size;

  // --- CSR build (per call; deterministic up to fp-sum order) ---
  hipMemsetAsync(cnt, 0, (size_t)N * 4, stream);
  k_count<<<EB, 256, 0, stream>>>(edges, cnt, E);
  k_dinv <<<NB, 256, 0, stream>>>(cnt, dinv, N);
  k_scan1<<<NB, 256, 0, stream>>>(cnt, incl, bsum, N);
  k_scan2<<<1, 256, 0, stream>>>(bsum, NB);
  k_scan3<<<NB, 256, 0, stream>>>(incl, cnt, bsum, offs, curs, N, E);
  k_fill <<<EB, 256, 0, stream>>>(edges, curs, csr, E);

  int GB = (N + 63) / 64;
  int AB = (N + 1) / 2;

  // conv1: h1 = agg(x @ W_in) + b_in
  k_gemm<<<GB, 256, 0, stream>>>(x, W_in, dinv, t, N);
  k_agg <<<AB, 256, 0, stream>>>(t, offs, csr, dinv, b_in, h, N, 0);
  // conv2: h2 = relu(agg(h1 @ W1) + b1)
  k_gemm<<<GB, 256, 0, stream>>>(h, W1, dinv, t, N);
  k_agg <<<AB, 256, 0, stream>>>(t, offs, csr, dinv, b1, h, N, 1);
  // conv3: h3 = relu(agg(h2 @ W2) + b2)
  k_gemm<<<GB, 256, 0, stream>>>(h, W2, dinv, t, N);
  k_agg <<<AB, 256, 0, stream>>>(t, offs, csr, dinv, b2, h, N, 1);

  // head + log_softmax
  int HB = 1568;
  k_head<<<HB, 256, 0, stream>>>(h, Wo, bo, out, N, HB * 4);
}

// Round 2
// 511.094 us; speedup vs baseline: 1.0308x; 1.0308x over previous
//
#include <hip/hip_runtime.h>
#include <math.h>

#define NEG_INF (-3.402823466e38f)

// ===================== CSR build =====================
__global__ void k_count(const int* __restrict__ edges, int* __restrict__ cnt, int E) {
  int e = blockIdx.x * 256 + threadIdx.x;
  if (e < E) atomicAdd(&cnt[edges[E + e]], 1);
}

__global__ void k_dinv(const int* __restrict__ cnt, float* __restrict__ dinv, int n) {
  int i = blockIdx.x * 256 + threadIdx.x;
  if (i < n) dinv[i] = rsqrtf((float)cnt[i] + 1.0f);  // +1 = self loop
}

__global__ void k_scan1(const int* __restrict__ cnt, int* __restrict__ incl,
                        int* __restrict__ bsum, int n) {
  __shared__ int s[256];
  int tid = threadIdx.x;
  int gid = blockIdx.x * 256 + tid;
  int x = (gid < n) ? cnt[gid] : 0;
  s[tid] = x;
  __syncthreads();
  #pragma unroll
  for (int off = 1; off < 256; off <<= 1) {
    int t = (tid >= off) ? s[tid - off] : 0;
    __syncthreads();
    x += t; s[tid] = x;
    __syncthreads();
  }
  incl[gid] = x;
  if (tid == 255) bsum[blockIdx.x] = x;
}

__global__ void k_scan2(int* __restrict__ bsum, int nb) {
  __shared__ int s[256];
  int tid = threadIdx.x;
  int x = (tid < nb) ? bsum[tid] : 0;
  s[tid] = x;
  __syncthreads();
  #pragma unroll
  for (int off = 1; off < 256; off <<= 1) {
    int t = (tid >= off) ? s[tid - off] : 0;
    __syncthreads();
    x += t; s[tid] = x;
    __syncthreads();
  }
  if (tid < nb) bsum[tid] = x;
}

__global__ void k_scan3(const int* __restrict__ incl, const int* __restrict__ cnt,
                        const int* __restrict__ bsum, int* __restrict__ offs,
                        int* __restrict__ curs, int n, int E) {
  int gid = blockIdx.x * 256 + threadIdx.x;
  if (gid < n) {
    int base = (blockIdx.x > 0) ? bsum[blockIdx.x - 1] : 0;
    int v = incl[gid] - cnt[gid] + base;   // exclusive
    offs[gid] = v;
    curs[gid] = v;
  }
  if (gid == 0) offs[n] = E;
}

__global__ void k_fill(const int* __restrict__ edges, int* __restrict__ curs,
                       int* __restrict__ csr, int E) {
  int e = blockIdx.x * 256 + threadIdx.x;
  if (e < E) {
    int s = edges[e];
    int d = edges[E + e];
    int pos = atomicAdd(&curs[d], 1);
    csr[pos] = s;
  }
}

// ===================== dense GEMM: T = (A @ W) * dinv[row] =====================
// A [n,128], W [128,128] row-major. Block: 256 thr, 64 rows x 128 cols.
__global__ __launch_bounds__(256) void k_gemm(
    const float* __restrict__ A, const float* __restrict__ W,
    const float* __restrict__ dinv, float* __restrict__ T, int n)
{
  __shared__ float sW[128 * 128];   // 64 KB
  __shared__ float sX[128 * 64];    // 32 KB, transposed: (k,r) at k*64 + (r ^ swz(k))
  int tid = threadIdx.x;
  int rbase = blockIdx.x * 64;

  {
    const float4* W4 = (const float4*)W;
    float4* sW4 = (float4*)sW;
    #pragma unroll
    for (int i = 0; i < 16; ++i) sW4[i * 256 + tid] = W4[i * 256 + tid];
  }
  {
    int k4 = tid & 31;        // float4 index within a row: k = 4*k4+j
    int r0 = tid >> 5;        // 0..7
    int swz = (k4 & 7) << 2;  // ((k>>2)&7)<<2
    #pragma unroll
    for (int l = 0; l < 8; ++l) {
      int r = r0 + (l << 3);
      int row = rbase + r;
      float4 v = make_float4(0.f, 0.f, 0.f, 0.f);
      if (row < n) v = *(const float4*)(A + (size_t)row * 128 + (k4 << 2));
      int rs = r ^ swz;
      sX[(k4 * 4 + 0) * 64 + rs] = v.x;
      sX[(k4 * 4 + 1) * 64 + rs] = v.y;
      sX[(k4 * 4 + 2) * 64 + rs] = v.z;
      sX[(k4 * 4 + 3) * 64 + rs] = v.w;
    }
  }
  __syncthreads();

  int cg = tid & 15;   // cols cg*8 .. cg*8+7
  int rg = tid >> 4;   // rows rg*4 .. rg*4+3
  float acc[4][8];
  #pragma unroll
  for (int i = 0; i < 4; ++i)
    #pragma unroll
    for (int j = 0; j < 8; ++j) acc[i][j] = 0.f;

  #pragma unroll 4
  for (int k = 0; k < 128; ++k) {
    int swz = ((k >> 2) & 7) << 2;
    float4 xv = *(const float4*)(sX + k * 64 + ((rg << 2) ^ swz));
    float4 wa = *(const float4*)(sW + k * 128 + (cg << 3));
    float4 wb = *(const float4*)(sW + k * 128 + (cg << 3) + 4);
    float xr[4] = {xv.x, xv.y, xv.z, xv.w};
    float wr[8] = {wa.x, wa.y, wa.z, wa.w, wb.x, wb.y, wb.z, wb.w};
    #pragma unroll
    for (int i = 0; i < 4; ++i)
      #pragma unroll
      for (int j = 0; j < 8; ++j)
        acc[i][j] = fmaf(xr[i], wr[j], acc[i][j]);
  }

  #pragma unroll
  for (int i = 0; i < 4; ++i) {
    int row = rbase + (rg << 2) + i;
    if (row < n) {
      float s = dinv[row];
      float4 o0 = make_float4(acc[i][0]*s, acc[i][1]*s, acc[i][2]*s, acc[i][3]*s);
      float4 o1 = make_float4(acc[i][4]*s, acc[i][5]*s, acc[i][6]*s, acc[i][7]*s);
      float* dst = T + (size_t)row * 128 + (cg << 3);
      *(float4*)dst = o0;
      *(float4*)(dst + 4) = o1;
    }
  }
}

// ===================== sparse aggregate =====================
// Wave per node; each lane owns 2 columns (float2). One neighbor row =
// one 512B wave transaction. 4 nodes per 256-thread block.
__global__ __launch_bounds__(256) void k_agg(
    const float* __restrict__ T, const int* __restrict__ offs,
    const int* __restrict__ csr, const float* __restrict__ dinv,
    const float* __restrict__ bias, float* __restrict__ H, int n, int relu)
{
  int u = (blockIdx.x << 2) + (threadIdx.x >> 6);
  if (u >= n) return;
  int lane = threadIdx.x & 63;
  const float2* T2 = (const float2*)T;
  float2 a = T2[(size_t)u * 64 + lane];   // self loop (T row already * dinv[u])
  float ax = a.x, ay = a.y;
  int e0 = offs[u], e1 = offs[u + 1];
  int e = e0;
  for (; e + 4 <= e1; e += 4) {
    int s0 = csr[e], s1 = csr[e + 1], s2 = csr[e + 2], s3 = csr[e + 3];
    float2 v0 = T2[(size_t)s0 * 64 + lane];
    float2 v1 = T2[(size_t)s1 * 64 + lane];
    float2 v2 = T2[(size_t)s2 * 64 + lane];
    float2 v3 = T2[(size_t)s3 * 64 + lane];
    ax += (v0.x + v1.x) + (v2.x + v3.x);
    ay += (v0.y + v1.y) + (v2.y + v3.y);
  }
  for (; e < e1; ++e) {
    float2 v = T2[(size_t)csr[e] * 64 + lane];
    ax += v.x; ay += v.y;
  }
  float du = dinv[u];
  float2 b2 = *(const float2*)(bias + (lane << 1));
  float2 o;
  o.x = fmaf(ax, du, b2.x);
  o.y = fmaf(ay, du, b2.y);
  if (relu) { o.x = fmaxf(o.x, 0.f); o.y = fmaxf(o.y, 0.f); }
  *((float2*)H + (size_t)u * 64 + lane) = o;
}

// ===================== head: logits + log_softmax =====================
// Wave per row. Wo staged in LDS (20 KB/block). Each lane holds float2 of the
// H row; broadcast h_k to all lanes via __shfl. Lane c<40 computes logit c.
__global__ __launch_bounds__(256) void k_head(
    const float* __restrict__ H, const float* __restrict__ Wo,
    const float* __restrict__ bo, float* __restrict__ out, int n, int nwaves)
{
  __shared__ float sWo[128 * 40];   // 20 KB
  for (int i = threadIdx.x; i < 128 * 40; i += 256) sWo[i] = Wo[i];
  __syncthreads();

  int lane = threadIdx.x & 63;
  int wid = (blockIdx.x << 2) + (threadIdx.x >> 6);
  int cc = (lane < 40) ? lane : 0;
  float bv = bo[cc];

  for (int r = wid; r < n; r += nwaves) {
    float2 hv = *(const float2*)(H + (size_t)r * 128 + (lane << 1));
    float acc = bv;
    #pragma unroll
    for (int k = 0; k < 64; ++k) {
      float h0 = __shfl(hv.x, k);
      float h1 = __shfl(hv.y, k);
      acc = fmaf(h0, sWo[(2 * k) * 40 + cc], acc);
      acc = fmaf(h1, sWo[(2 * k + 1) * 40 + cc], acc);
    }
    float m = (lane < 40) ? acc : NEG_INF;
    #pragma unroll
    for (int o = 32; o; o >>= 1) m = fmaxf(m, __shfl_xor(m, o));
    float ex = (lane < 40) ? __expf(acc - m) : 0.f;
    float s = ex;
    #pragma unroll
    for (int o = 32; o; o >>= 1) s += __shfl_xor(s, o);
    if (lane < 40) out[(size_t)r * 40 + lane] = acc - m - __logf(s);
  }
}

// ===================== launch =====================
extern "C" void kernel_launch(void* const* d_in, const int* in_sizes, int n_in,
                              void* d_out, int out_size, void* d_ws, size_t ws_size,
                              hipStream_t stream) {
  const float* x    = (const float*)d_in[0];
  const int*   edges= (const int*)d_in[1];
  const float* W_in = (const float*)d_in[2];
  const float* b_in = (const float*)d_in[3];
  const float* W1   = (const float*)d_in[4];
  const float* b1   = (const float*)d_in[5];
  const float* W2   = (const float*)d_in[6];
  const float* b2   = (const float*)d_in[7];
  const float* Wo   = (const float*)d_in[8];
  const float* bo   = (const float*)d_in[9];
  float* out = (float*)d_out;

  int N = in_sizes[0] / 128;
  int E = in_sizes[1] / 2;
  int NB = (N + 255) / 256;
  int EB = (E + 255) / 256;

  char* p = (char*)d_ws;
  auto alloc = [&](size_t bytes) {
    char* r = p; p += (bytes + 255) & ~(size_t)255; return r;
  };
  float* t    = (float*)alloc((size_t)N * 128 * 4);
  float* h    = (float*)alloc((size_t)N * 128 * 4);
  int*   cnt  = (int*)  alloc((size_t)N * 4);
  float* dinv = (float*)alloc((size_t)N * 4);
  int*   incl = (int*)  alloc((size_t)NB * 256 * 4);
  int*   bsum = (int*)  alloc(256 * 4);
  int*   offs = (int*)  alloc((size_t)(N + 1) * 4);
  int*   curs = (int*)  alloc((size_t)N * 4);
  int*   csr  = (int*)  alloc((size_t)E * 4);
  (void)ws_size; (void)n_in; (void)out_size;

  // --- CSR build (per call; deterministic up to fp-sum order) ---
  hipMemsetAsync(cnt, 0, (size_t)N * 4, stream);
  k_count<<<EB, 256, 0, stream>>>(edges, cnt, E);
  k_dinv <<<NB, 256, 0, stream>>>(cnt, dinv, N);
  k_scan1<<<NB, 256, 0, stream>>>(cnt, incl, bsum, N);
  k_scan2<<<1, 256, 0, stream>>>(bsum, NB);
  k_scan3<<<NB, 256, 0, stream>>>(incl, cnt, bsum, offs, curs, N, E);
  k_fill <<<EB, 256, 0, stream>>>(edges, curs, csr, E);

  int GB = (N + 63) / 64;
  int AB = (N + 3) / 4;

  // conv1: h1 = agg(x @ W_in) + b_in
  k_gemm<<<GB, 256, 0, stream>>>(x, W_in, dinv, t, N);
  k_agg <<<AB, 256, 0, stream>>>(t, offs, csr, dinv, b_in, h, N, 0);
  // conv2: h2 = relu(agg(h1 @ W1) + b1)
  k_gemm<<<GB, 256, 0, stream>>>(h, W1, dinv, t, N);
  k_agg <<<AB, 256, 0, stream>>>(t, offs, csr, dinv, b1, h, N, 1);
  // conv3: h3 = relu(agg(h2 @ W2) + b2)
  k_gemm<<<GB, 256, 0, stream>>>(h, W2, dinv, t, N);
  k_agg <<<AB, 256, 0, stream>>>(t, offs, csr, dinv, b2, h, N, 1);

  // head + log_softmax
  int HB = 1024;
  k_head<<<HB, 256, 0, stream>>>(h, Wo, bo, out, N, HB * 4);
}

// Round 3
// 390.889 us; speedup vs baseline: 1.3477x; 1.3075x over previous
//
#include <hip/hip_runtime.h>
#include <hip/hip_bf16.h>
#include <math.h>

#define NEG_INF (-3.402823466e38f)
typedef unsigned int uint;
typedef unsigned short ushort;

__device__ __forceinline__ float bf_lo(uint u) { return __uint_as_float(u << 16); }
__device__ __forceinline__ float bf_hi(uint u) { return __uint_as_float(u & 0xffff0000u); }
__device__ __forceinline__ ushort f2bf(float f) {
  __hip_bfloat16 h = __float2bfloat16(f);   // RNE
  return *reinterpret_cast<ushort*>(&h);
}
__device__ __forceinline__ uint pack2(float a, float b) {
  return (uint)f2bf(a) | ((uint)f2bf(b) << 16);
}

// ===================== CSR build =====================
__global__ void k_count(const int* __restrict__ edges, int* __restrict__ cnt, int E) {
  int e = blockIdx.x * 256 + threadIdx.x;
  if (e < E) atomicAdd(&cnt[edges[E + e]], 1);
}

__global__ void k_dinv(const int* __restrict__ cnt, float* __restrict__ dinv, int n) {
  int i = blockIdx.x * 256 + threadIdx.x;
  if (i < n) dinv[i] = rsqrtf((float)cnt[i] + 1.0f);  // +1 = self loop
}

__global__ void k_scan1(const int* __restrict__ cnt, int* __restrict__ incl,
                        int* __restrict__ bsum, int n) {
  __shared__ int s[256];
  int tid = threadIdx.x;
  int gid = blockIdx.x * 256 + tid;
  int x = (gid < n) ? cnt[gid] : 0;
  s[tid] = x;
  __syncthreads();
  #pragma unroll
  for (int off = 1; off < 256; off <<= 1) {
    int t = (tid >= off) ? s[tid - off] : 0;
    __syncthreads();
    x += t; s[tid] = x;
    __syncthreads();
  }
  incl[gid] = x;
  if (tid == 255) bsum[blockIdx.x] = x;
}

__global__ void k_scan2(int* __restrict__ bsum, int nb) {
  __shared__ int s[256];
  int tid = threadIdx.x;
  int x = (tid < nb) ? bsum[tid] : 0;
  s[tid] = x;
  __syncthreads();
  #pragma unroll
  for (int off = 1; off < 256; off <<= 1) {
    int t = (tid >= off) ? s[tid - off] : 0;
    __syncthreads();
    x += t; s[tid] = x;
    __syncthreads();
  }
  if (tid < nb) bsum[tid] = x;
}

__global__ void k_scan3(const int* __restrict__ incl, const int* __restrict__ cnt,
                        const int* __restrict__ bsum, int* __restrict__ offs,
                        int* __restrict__ curs, int n, int E) {
  int gid = blockIdx.x * 256 + threadIdx.x;
  if (gid < n) {
    int base = (blockIdx.x > 0) ? bsum[blockIdx.x - 1] : 0;
    int v = incl[gid] - cnt[gid] + base;   // exclusive
    offs[gid] = v;
    curs[gid] = v;
  }
  if (gid == 0) offs[n] = E;
}

__global__ void k_fill(const int* __restrict__ edges, int* __restrict__ curs,
                       int* __restrict__ csr, int E) {
  int e = blockIdx.x * 256 + threadIdx.x;
  if (e < E) {
    int s = edges[e];
    int d = edges[E + e];
    int pos = atomicAdd(&curs[d], 1);
    csr[pos] = s;
  }
}

// ===================== dense GEMM: T = bf16( (A @ W) * dinv[row] ) =====================
// A [n,128] fp32, W [128,128] fp32 row-major, T [n,128] bf16.
// Block: 256 thr, 64 rows x 128 cols.
__global__ __launch_bounds__(256) void k_gemm(
    const float* __restrict__ A, const float* __restrict__ W,
    const float* __restrict__ dinv, ushort* __restrict__ T, int n)
{
  __shared__ float sW[128 * 128];   // 64 KB
  __shared__ float sX[128 * 64];    // 32 KB, transposed: (k,r) at k*64 + (r ^ swz(k))
  int tid = threadIdx.x;
  int rbase = blockIdx.x * 64;

  {
    const float4* W4 = (const float4*)W;
    float4* sW4 = (float4*)sW;
    #pragma unroll
    for (int i = 0; i < 16; ++i) sW4[i * 256 + tid] = W4[i * 256 + tid];
  }
  {
    int k4 = tid & 31;        // float4 index within a row: k = 4*k4+j
    int r0 = tid >> 5;        // 0..7
    int swz = (k4 & 7) << 2;  // ((k>>2)&7)<<2
    #pragma unroll
    for (int l = 0; l < 8; ++l) {
      int r = r0 + (l << 3);
      int row = rbase + r;
      float4 v = make_float4(0.f, 0.f, 0.f, 0.f);
      if (row < n) v = *(const float4*)(A + (size_t)row * 128 + (k4 << 2));
      int rs = r ^ swz;
      sX[(k4 * 4 + 0) * 64 + rs] = v.x;
      sX[(k4 * 4 + 1) * 64 + rs] = v.y;
      sX[(k4 * 4 + 2) * 64 + rs] = v.z;
      sX[(k4 * 4 + 3) * 64 + rs] = v.w;
    }
  }
  __syncthreads();

  int cg = tid & 15;   // cols cg*8 .. cg*8+7
  int rg = tid >> 4;   // rows rg*4 .. rg*4+3
  float acc[4][8];
  #pragma unroll
  for (int i = 0; i < 4; ++i)
    #pragma unroll
    for (int j = 0; j < 8; ++j) acc[i][j] = 0.f;

  #pragma unroll 4
  for (int k = 0; k < 128; ++k) {
    int swz = ((k >> 2) & 7) << 2;
    float4 xv = *(const float4*)(sX + k * 64 + ((rg << 2) ^ swz));
    float4 wa = *(const float4*)(sW + k * 128 + (cg << 3));
    float4 wb = *(const float4*)(sW + k * 128 + (cg << 3) + 4);
    float xr[4] = {xv.x, xv.y, xv.z, xv.w};
    float wr[8] = {wa.x, wa.y, wa.z, wa.w, wb.x, wb.y, wb.z, wb.w};
    #pragma unroll
    for (int i = 0; i < 4; ++i)
      #pragma unroll
      for (int j = 0; j < 8; ++j)
        acc[i][j] = fmaf(xr[i], wr[j], acc[i][j]);
  }

  #pragma unroll
  for (int i = 0; i < 4; ++i) {
    int row = rbase + (rg << 2) + i;
    if (row < n) {
      float s = dinv[row];
      uint4 pk;
      pk.x = pack2(acc[i][0] * s, acc[i][1] * s);
      pk.y = pack2(acc[i][2] * s, acc[i][3] * s);
      pk.z = pack2(acc[i][4] * s, acc[i][5] * s);
      pk.w = pack2(acc[i][6] * s, acc[i][7] * s);
      ((uint4*)(T + (size_t)row * 128))[cg] = pk;
    }
  }
}

// ===================== sparse aggregate =====================
// Wave per node; lane owns 2 bf16 columns (one uint). Neighbor row = 256B
// wave transaction. fp32 accumulation. 4 nodes per 256-thread block.
__global__ __launch_bounds__(256) void k_agg(
    const ushort* __restrict__ T, const int* __restrict__ offs,
    const int* __restrict__ csr, const float* __restrict__ dinv,
    const float* __restrict__ bias, float* __restrict__ H, int n, int relu)
{
  int u = (blockIdx.x << 2) + (threadIdx.x >> 6);
  if (u >= n) return;
  int lane = threadIdx.x & 63;
  const uint* Tu = (const uint*)T;
  uint su = Tu[(size_t)u * 64 + lane];   // self loop (row already * dinv[u])
  float ax = bf_lo(su), ay = bf_hi(su);
  int e0 = offs[u], e1 = offs[u + 1];
  int e = e0;
  for (; e + 4 <= e1; e += 4) {
    int s0 = csr[e], s1 = csr[e + 1], s2 = csr[e + 2], s3 = csr[e + 3];
    uint v0 = Tu[(size_t)s0 * 64 + lane];
    uint v1 = Tu[(size_t)s1 * 64 + lane];
    uint v2 = Tu[(size_t)s2 * 64 + lane];
    uint v3 = Tu[(size_t)s3 * 64 + lane];
    ax += (bf_lo(v0) + bf_lo(v1)) + (bf_lo(v2) + bf_lo(v3));
    ay += (bf_hi(v0) + bf_hi(v1)) + (bf_hi(v2) + bf_hi(v3));
  }
  for (; e < e1; ++e) {
    uint v = Tu[(size_t)csr[e] * 64 + lane];
    ax += bf_lo(v); ay += bf_hi(v);
  }
  float du = dinv[u];
  float2 b2 = *(const float2*)(bias + (lane << 1));
  float2 o;
  o.x = fmaf(ax, du, b2.x);
  o.y = fmaf(ay, du, b2.y);
  if (relu) { o.x = fmaxf(o.x, 0.f); o.y = fmaxf(o.y, 0.f); }
  *((float2*)H + (size_t)u * 64 + lane) = o;
}

// ===================== head: logits + fused log_softmax =====================
// Mini-GEMM, k_gemm structure: 256 thr, 64 rows x 40 cols per block.
// Thread (cg=tid&7, rg=tid>>3) owns rows rg*2..rg*2+1, cols cg*5..cg*5+4.
// Softmax reduced across the 8 col-group lanes via __shfl_xor(1,2,4).
__global__ __launch_bounds__(256) void k_head(
    const float* __restrict__ H, const float* __restrict__ Wo,
    const float* __restrict__ bo, float* __restrict__ out, int n)
{
  __shared__ float sWo[128 * 40];   // 20 KB
  __shared__ float sX[128 * 64];    // 32 KB, swizzled transpose
  int tid = threadIdx.x;
  int rbase = blockIdx.x * 64;

  {
    const float4* Wo4 = (const float4*)Wo;
    float4* sWo4 = (float4*)sWo;
    #pragma unroll
    for (int i = 0; i < 5; ++i) sWo4[i * 256 + tid] = Wo4[i * 256 + tid];
  }
  {
    int k4 = tid & 31;
    int r0 = tid >> 5;
    int swz = (k4 & 7) << 2;
    #pragma unroll
    for (int l = 0; l < 8; ++l) {
      int r = r0 + (l << 3);
      int row = rbase + r;
      float4 v = make_float4(0.f, 0.f, 0.f, 0.f);
      if (row < n) v = *(const float4*)(H + (size_t)row * 128 + (k4 << 2));
      int rs = r ^ swz;
      sX[(k4 * 4 + 0) * 64 + rs] = v.x;
      sX[(k4 * 4 + 1) * 64 + rs] = v.y;
      sX[(k4 * 4 + 2) * 64 + rs] = v.z;
      sX[(k4 * 4 + 3) * 64 + rs] = v.w;
    }
  }
  __syncthreads();

  int cg = tid & 7;    // 8 col groups x 5 cols
  int rg = tid >> 3;   // 32 row groups x 2 rows
  float bj[5];
  #pragma unroll
  for (int j = 0; j < 5; ++j) bj[j] = bo[cg * 5 + j];
  float acc[2][5];
  #pragma unroll
  for (int i = 0; i < 2; ++i)
    #pragma unroll
    for (int j = 0; j < 5; ++j) acc[i][j] = bj[j];

  #pragma unroll 4
  for (int k = 0; k < 128; ++k) {
    int swz = ((k >> 2) & 7) << 2;
    float2 xv = *(const float2*)(sX + k * 64 + ((rg << 1) ^ swz));
    const float* wr = sWo + k * 40 + cg * 5;
    float w0 = wr[0], w1 = wr[1], w2 = wr[2], w3 = wr[3], w4 = wr[4];
    acc[0][0] = fmaf(xv.x, w0, acc[0][0]);
    acc[0][1] = fmaf(xv.x, w1, acc[0][1]);
    acc[0][2] = fmaf(xv.x, w2, acc[0][2]);
    acc[0][3] = fmaf(xv.x, w3, acc[0][3]);
    acc[0][4] = fmaf(xv.x, w4, acc[0][4]);
    acc[1][0] = fmaf(xv.y, w0, acc[1][0]);
    acc[1][1] = fmaf(xv.y, w1, acc[1][1]);
    acc[1][2] = fmaf(xv.y, w2, acc[1][2]);
    acc[1][3] = fmaf(xv.y, w3, acc[1][3]);
    acc[1][4] = fmaf(xv.y, w4, acc[1][4]);
  }

  #pragma unroll
  for (int i = 0; i < 2; ++i) {
    int row = rbase + (rg << 1) + i;
    float m = acc[i][0];
    m = fmaxf(m, acc[i][1]); m = fmaxf(m, acc[i][2]);
    m = fmaxf(m, acc[i][3]); m = fmaxf(m, acc[i][4]);
    m = fmaxf(m, __shfl_xor(m, 1));
    m = fmaxf(m, __shfl_xor(m, 2));
    m = fmaxf(m, __shfl_xor(m, 4));
    float s = 0.f;
    #pragma unroll
    for (int j = 0; j < 5; ++j) s += __expf(acc[i][j] - m);
    s += __shfl_xor(s, 1);
    s += __shfl_xor(s, 2);
    s += __shfl_xor(s, 4);
    float ls = m + __logf(s);
    if (row < n) {
      float* dst = out + (size_t)row * 40 + cg * 5;
      #pragma unroll
      for (int j = 0; j < 5; ++j) dst[j] = acc[i][j] - ls;
    }
  }
}

// ===================== launch =====================
extern "C" void kernel_launch(void* const* d_in, const int* in_sizes, int n_in,
                              void* d_out, int out_size, void* d_ws, size_t ws_size,
                              hipStream_t stream) {
  const float* x    = (const float*)d_in[0];
  const int*   edges= (const int*)d_in[1];
  const float* W_in = (const float*)d_in[2];
  const float* b_in = (const float*)d_in[3];
  const float* W1   = (const float*)d_in[4];
  const float* b1   = (const float*)d_in[5];
  const float* W2   = (const float*)d_in[6];
  const float* b2   = (const float*)d_in[7];
  const float* Wo   = (const float*)d_in[8];
  const float* bo   = (const float*)d_in[9];
  float* out = (float*)d_out;

  int N = in_sizes[0] / 128;
  int E = in_sizes[1] / 2;
  int NB = (N + 255) / 256;
  int EB = (E + 255) / 256;

  char* p = (char*)d_ws;
  auto alloc = [&](size_t bytes) {
    char* r = p; p += (bytes + 255) & ~(size_t)255; return r;
  };
  ushort* t   = (ushort*)alloc((size_t)N * 128 * 2);
  float* h    = (float*)alloc((size_t)N * 128 * 4);
  int*   cnt  = (int*)  alloc((size_t)N * 4);
  float* dinv = (float*)alloc((size_t)N * 4);
  int*   incl = (int*)  alloc((size_t)NB * 256 * 4);
  int*   bsum = (int*)  alloc(256 * 4);
  int*   offs = (int*)  alloc((size_t)(N + 1) * 4);
  int*   curs = (int*)  alloc((size_t)N * 4);
  int*   csr  = (int*)  alloc((size_t)E * 4);
  (void)ws_size; (void)n_in; (void)out_size;

  // --- CSR build ---
  hipMemsetAsync(cnt, 0, (size_t)N * 4, stream);
  k_count<<<EB, 256, 0, stream>>>(edges, cnt, E);
  k_dinv <<<NB, 256, 0, stream>>>(cnt, dinv, N);
  k_scan1<<<NB, 256, 0, stream>>>(cnt, incl, bsum, N);
  k_scan2<<<1, 256, 0, stream>>>(bsum, NB);
  k_scan3<<<NB, 256, 0, stream>>>(incl, cnt, bsum, offs, curs, N, E);
  k_fill <<<EB, 256, 0, stream>>>(edges, curs, csr, E);

  int GB = (N + 63) / 64;
  int AB = (N + 3) / 4;

  // conv1: h1 = agg(x @ W_in) + b_in
  k_gemm<<<GB, 256, 0, stream>>>(x, W_in, dinv, t, N);
  k_agg <<<AB, 256, 0, stream>>>(t, offs, csr, dinv, b_in, h, N, 0);
  // conv2: h2 = relu(agg(h1 @ W1) + b1)
  k_gemm<<<GB, 256, 0, stream>>>(h, W1, dinv, t, N);
  k_agg <<<AB, 256, 0, stream>>>(t, offs, csr, dinv, b1, h, N, 1);
  // conv3: h3 = relu(agg(h2 @ W2) + b2)
  k_gemm<<<GB, 256, 0, stream>>>(h, W2, dinv, t, N);
  k_agg <<<AB, 256, 0, stream>>>(t, offs, csr, dinv, b2, h, N, 1);

  // head + log_softmax (fused)
  k_head<<<GB, 256, 0, stream>>>(h, Wo, bo, out, N);
}

// Round 4
// 274.504 us; speedup vs baseline: 1.9191x; 1.4240x over previous
//
#include <hip/hip_runtime.h>
#include <hip/hip_bf16.h>
#include <math.h>

typedef unsigned int uint;
typedef unsigned short ushort;
typedef __attribute__((ext_vector_type(8))) short short8;   // 8 bf16 = 4 VGPRs
typedef __attribute__((ext_vector_type(4))) float f32x4;    // MFMA accumulator

__device__ __forceinline__ float bf_lo(uint u) { return __uint_as_float(u << 16); }
__device__ __forceinline__ float bf_hi(uint u) { return __uint_as_float(u & 0xffff0000u); }
__device__ __forceinline__ ushort f2bf(float f) {
  __hip_bfloat16 h = __float2bfloat16(f);   // RNE
  return *reinterpret_cast<ushort*>(&h);
}
__device__ __forceinline__ uint pack2(float a, float b) {
  return (uint)f2bf(a) | ((uint)f2bf(b) << 16);
}

// ===================== CSR build =====================
__global__ void k_count(const int* __restrict__ edges, int* __restrict__ cnt, int E) {
  int e = blockIdx.x * 256 + threadIdx.x;
  if (e < E) atomicAdd(&cnt[edges[E + e]], 1);
}

__global__ void k_dinv(const int* __restrict__ cnt, float* __restrict__ dinv, int n) {
  int i = blockIdx.x * 256 + threadIdx.x;
  if (i < n) dinv[i] = rsqrtf((float)cnt[i] + 1.0f);  // +1 = self loop
}

__global__ void k_scan1(const int* __restrict__ cnt, int* __restrict__ incl,
                        int* __restrict__ bsum, int n) {
  __shared__ int s[256];
  int tid = threadIdx.x;
  int gid = blockIdx.x * 256 + tid;
  int x = (gid < n) ? cnt[gid] : 0;
  s[tid] = x;
  __syncthreads();
  #pragma unroll
  for (int off = 1; off < 256; off <<= 1) {
    int t = (tid >= off) ? s[tid - off] : 0;
    __syncthreads();
    x += t; s[tid] = x;
    __syncthreads();
  }
  incl[gid] = x;
  if (tid == 255) bsum[blockIdx.x] = x;
}

__global__ void k_scan2(int* __restrict__ bsum, int nb) {
  __shared__ int s[256];
  int tid = threadIdx.x;
  int x = (tid < nb) ? bsum[tid] : 0;
  s[tid] = x;
  __syncthreads();
  #pragma unroll
  for (int off = 1; off < 256; off <<= 1) {
    int t = (tid >= off) ? s[tid - off] : 0;
    __syncthreads();
    x += t; s[tid] = x;
    __syncthreads();
  }
  if (tid < nb) bsum[tid] = x;
}

__global__ void k_scan3(const int* __restrict__ incl, const int* __restrict__ cnt,
                        const int* __restrict__ bsum, int* __restrict__ offs,
                        int* __restrict__ curs, int n, int E) {
  int gid = blockIdx.x * 256 + threadIdx.x;
  if (gid < n) {
    int base = (blockIdx.x > 0) ? bsum[blockIdx.x - 1] : 0;
    int v = incl[gid] - cnt[gid] + base;   // exclusive
    offs[gid] = v;
    curs[gid] = v;
  }
  if (gid == 0) offs[n] = E;
}

__global__ void k_fill(const int* __restrict__ edges, int* __restrict__ curs,
                       int* __restrict__ csr, int E) {
  int e = blockIdx.x * 256 + threadIdx.x;
  if (e < E) {
    int s = edges[e];
    int d = edges[E + e];
    int pos = atomicAdd(&curs[d], 1);
    csr[pos] = s;
  }
}

// ===================== W prep: fp32 [k][c] -> bf16 Wt [col][k] =====================
// 24 blocks: 8 per matrix; chunk id = col*16 + kc (16B chunks of 8 k-elems).
__global__ void k_prepw(const float* __restrict__ W_in, const float* __restrict__ W1,
                        const float* __restrict__ W2, ushort* __restrict__ Wt) {
  int b = blockIdx.x;
  const float* W = (b < 8) ? W_in : (b < 16) ? W1 : W2;
  ushort* dst = Wt + (size_t)(b >> 3) * 16384;
  int id = (b & 7) * 256 + threadIdx.x;    // 0..2047
  int col = id >> 4, kc = id & 15;
  const float* src = W + (size_t)(kc * 8) * 128 + col;
  uint4 pk;
  pk.x = pack2(src[0],       src[128]);
  pk.y = pack2(src[2 * 128], src[3 * 128]);
  pk.z = pack2(src[4 * 128], src[5 * 128]);
  pk.w = pack2(src[6 * 128], src[7 * 128]);
  ((uint4*)dst)[id] = pk;
}

// ===================== MFMA GEMM: T = bf16( (A @ W) * dinv[row] ) =====================
// Block 256 thr = 4 waves; wave = 16 rows x 128 cols via 8x mfma_f32_16x16x32_bf16.
// W (bf16, pre-transposed [col][k]) staged in LDS with kc ^= (col&7) swizzle. A read
// global->VGPR directly (16B/lane). AF32: A is fp32, converted inline.
template <bool AF32>
__global__ __launch_bounds__(256) void k_gemm(
    const void* __restrict__ Ap, const ushort* __restrict__ Wt,
    const float* __restrict__ dinv, ushort* __restrict__ T, int n)
{
  __shared__ ushort sW[128 * 128 / 8 * 8];   // 32 KB: chunk (col,kc') at col*16+kc'
  int tid = threadIdx.x;
  {
    const uint4* Wt4 = (const uint4*)Wt;
    uint4* sW4 = (uint4*)sW;
    #pragma unroll
    for (int j = 0; j < 8; ++j) {
      int id = j * 256 + tid;
      int col = id >> 4, kc = id & 15;
      sW4[(col << 4) | (kc ^ (col & 7))] = Wt4[id];
    }
  }
  __syncthreads();

  int wid = tid >> 6, lane = tid & 63;
  int lr = lane & 15;    // A-row / B-col / D-col within fragment
  int lg = lane >> 4;    // k-group
  int rbase = blockIdx.x * 64 + wid * 16;
  int arow = rbase + lr;
  bool valid = arow < n;

  f32x4 acc[8];
  #pragma unroll
  for (int cf = 0; cf < 8; ++cf) acc[cf] = (f32x4){0.f, 0.f, 0.f, 0.f};

  #pragma unroll
  for (int ks = 0; ks < 4; ++ks) {
    short8 a = {};
    if (valid) {
      if constexpr (AF32) {
        const float4* Af = (const float4*)((const float*)Ap + (size_t)arow * 128) + (ks * 4 + lg) * 2;
        float4 u = Af[0], w = Af[1];
        union { uint4 u4; short8 s8; } cv;
        cv.u4.x = pack2(u.x, u.y); cv.u4.y = pack2(u.z, u.w);
        cv.u4.z = pack2(w.x, w.y); cv.u4.w = pack2(w.z, w.w);
        a = cv.s8;
      } else {
        a = ((const short8*)((const ushort*)Ap + (size_t)arow * 128))[ks * 4 + lg];
      }
    }
    int kc = (ks << 2) | lg;
    #pragma unroll
    for (int cf = 0; cf < 8; ++cf) {
      int col = (cf << 4) | lr;
      const short8* bp = (const short8*)sW + ((col << 4) | (kc ^ (lr & 7)));
      acc[cf] = __builtin_amdgcn_mfma_f32_16x16x32_bf16(a, *bp, acc[cf], 0, 0, 0);
    }
  }

  // D: col = cf*16 + lr, row = rbase + lg*4 + v
  #pragma unroll
  for (int v = 0; v < 4; ++v) {
    int row = rbase + (lg << 2) + v;
    if (row < n) {
      float s = dinv[row];
      ushort* dst = T + (size_t)row * 128 + lr;
      #pragma unroll
      for (int cf = 0; cf < 8; ++cf) dst[cf << 4] = f2bf(acc[cf][v] * s);
    }
  }
}

// ===================== sparse aggregate (bf16 in, bf16 out, fp32 accum) =====================
__global__ __launch_bounds__(256) void k_agg(
    const ushort* __restrict__ T, const int* __restrict__ offs,
    const int* __restrict__ csr, const float* __restrict__ dinv,
    const float* __restrict__ bias, ushort* __restrict__ H, int n, int relu)
{
  int u = (blockIdx.x << 2) + (threadIdx.x >> 6);
  if (u >= n) return;
  int lane = threadIdx.x & 63;
  const uint* Tu = (const uint*)T;
  uint su = Tu[(size_t)u * 64 + lane];   // self loop (row already * dinv[u])
  float ax = bf_lo(su), ay = bf_hi(su);
  int e0 = offs[u], e1 = offs[u + 1];
  int e = e0;
  for (; e + 4 <= e1; e += 4) {
    int s0 = csr[e], s1 = csr[e + 1], s2 = csr[e + 2], s3 = csr[e + 3];
    uint v0 = Tu[(size_t)s0 * 64 + lane];
    uint v1 = Tu[(size_t)s1 * 64 + lane];
    uint v2 = Tu[(size_t)s2 * 64 + lane];
    uint v3 = Tu[(size_t)s3 * 64 + lane];
    ax += (bf_lo(v0) + bf_lo(v1)) + (bf_lo(v2) + bf_lo(v3));
    ay += (bf_hi(v0) + bf_hi(v1)) + (bf_hi(v2) + bf_hi(v3));
  }
  for (; e < e1; ++e) {
    uint v = Tu[(size_t)csr[e] * 64 + lane];
    ax += bf_lo(v); ay += bf_hi(v);
  }
  float du = dinv[u];
  float2 b2 = *(const float2*)(bias + (lane << 1));
  float ox = fmaf(ax, du, b2.x);
  float oy = fmaf(ay, du, b2.y);
  if (relu) { ox = fmaxf(ox, 0.f); oy = fmaxf(oy, 0.f); }
  ((uint*)H)[(size_t)u * 64 + lane] = pack2(ox, oy);
}

// ===================== head: logits + fused log_softmax (bf16 H) =====================
__global__ __launch_bounds__(256) void k_head(
    const ushort* __restrict__ H, const float* __restrict__ Wo,
    const float* __restrict__ bo, float* __restrict__ out, int n)
{
  __shared__ float sWo[128 * 40];   // 20 KB
  __shared__ float sX[128 * 64];    // 32 KB, swizzled transpose
  int tid = threadIdx.x;
  int rbase = blockIdx.x * 64;

  {
    const float4* Wo4 = (const float4*)Wo;
    float4* sWo4 = (float4*)sWo;
    #pragma unroll
    for (int i = 0; i < 5; ++i) sWo4[i * 256 + tid] = Wo4[i * 256 + tid];
  }
  {
    const uint4* H4 = (const uint4*)H;
    #pragma unroll
    for (int j = 0; j < 4; ++j) {
      int id = j * 256 + tid;
      int r = id & 63, kc8 = id >> 6;   // kc8 = 0..15, 8 k-elems each
      int row = rbase + r;
      uint4 v = make_uint4(0u, 0u, 0u, 0u);
      if (row < n) v = H4[(size_t)row * 16 + kc8];
      float f[8] = {bf_lo(v.x), bf_hi(v.x), bf_lo(v.y), bf_hi(v.y),
                    bf_lo(v.z), bf_hi(v.z), bf_lo(v.w), bf_hi(v.w)};
      #pragma unroll
      for (int j2 = 0; j2 < 8; ++j2) {
        int k = kc8 * 8 + j2;
        int swz = ((k >> 2) & 7) << 2;
        sX[k * 64 + (r ^ swz)] = f[j2];
      }
    }
  }
  __syncthreads();

  int cg = tid & 7;    // 8 col groups x 5 cols
  int rg = tid >> 3;   // 32 row groups x 2 rows
  float bj[5];
  #pragma unroll
  for (int j = 0; j < 5; ++j) bj[j] = bo[cg * 5 + j];
  float acc[2][5];
  #pragma unroll
  for (int i = 0; i < 2; ++i)
    #pragma unroll
    for (int j = 0; j < 5; ++j) acc[i][j] = bj[j];

  #pragma unroll 4
  for (int k = 0; k < 128; ++k) {
    int swz = ((k >> 2) & 7) << 2;
    float2 xv = *(const float2*)(sX + k * 64 + ((rg << 1) ^ swz));
    const float* wr = sWo + k * 40 + cg * 5;
    float w0 = wr[0], w1 = wr[1], w2 = wr[2], w3 = wr[3], w4 = wr[4];
    acc[0][0] = fmaf(xv.x, w0, acc[0][0]);
    acc[0][1] = fmaf(xv.x, w1, acc[0][1]);
    acc[0][2] = fmaf(xv.x, w2, acc[0][2]);
    acc[0][3] = fmaf(xv.x, w3, acc[0][3]);
    acc[0][4] = fmaf(xv.x, w4, acc[0][4]);
    acc[1][0] = fmaf(xv.y, w0, acc[1][0]);
    acc[1][1] = fmaf(xv.y, w1, acc[1][1]);
    acc[1][2] = fmaf(xv.y, w2, acc[1][2]);
    acc[1][3] = fmaf(xv.y, w3, acc[1][3]);
    acc[1][4] = fmaf(xv.y, w4, acc[1][4]);
  }

  #pragma unroll
  for (int i = 0; i < 2; ++i) {
    int row = rbase + (rg << 1) + i;
    float m = acc[i][0];
    m = fmaxf(m, acc[i][1]); m = fmaxf(m, acc[i][2]);
    m = fmaxf(m, acc[i][3]); m = fmaxf(m, acc[i][4]);
    m = fmaxf(m, __shfl_xor(m, 1));
    m = fmaxf(m, __shfl_xor(m, 2));
    m = fmaxf(m, __shfl_xor(m, 4));
    float s = 0.f;
    #pragma unroll
    for (int j = 0; j < 5; ++j) s += __expf(acc[i][j] - m);
    s += __shfl_xor(s, 1);
    s += __shfl_xor(s, 2);
    s += __shfl_xor(s, 4);
    float ls = m + __logf(s);
    if (row < n) {
      float* dst = out + (size_t)row * 40 + cg * 5;
      #pragma unroll
      for (int j = 0; j < 5; ++j) dst[j] = acc[i][j] - ls;
    }
  }
}

// ===================== launch =====================
extern "C" void kernel_launch(void* const* d_in, const int* in_sizes, int n_in,
                              void* d_out, int out_size, void* d_ws, size_t ws_size,
                              hipStream_t stream) {
  const float* x    = (const float*)d_in[0];
  const int*   edges= (const int*)d_in[1];
  const float* W_in = (const float*)d_in[2];
  const float* b_in = (const float*)d_in[3];
  const float* W1   = (const float*)d_in[4];
  const float* b1   = (const float*)d_in[5];
  const float* W2   = (const float*)d_in[6];
  const float* b2   = (const float*)d_in[7];
  const float* Wo   = (const float*)d_in[8];
  const float* bo   = (const float*)d_in[9];
  float* out = (float*)d_out;

  int N = in_sizes[0] / 128;
  int E = in_sizes[1] / 2;
  int NB = (N + 255) / 256;
  int EB = (E + 255) / 256;

  char* p = (char*)d_ws;
  auto alloc = [&](size_t bytes) {
    char* r = p; p += (bytes + 255) & ~(size_t)255; return r;
  };
  ushort* t   = (ushort*)alloc((size_t)N * 128 * 2);
  ushort* h   = (ushort*)alloc((size_t)N * 128 * 2);
  ushort* wt  = (ushort*)alloc(3 * 16384 * 2);
  int*   cnt  = (int*)  alloc((size_t)N * 4);
  float* dinv = (float*)alloc((size_t)N * 4);
  int*   incl = (int*)  alloc((size_t)NB * 256 * 4);
  int*   bsum = (int*)  alloc(256 * 4);
  int*   offs = (int*)  alloc((size_t)(N + 1) * 4);
  int*   curs = (int*)  alloc((size_t)N * 4);
  int*   csr  = (int*)  alloc((size_t)E * 4);
  (void)ws_size; (void)n_in; (void)out_size;

  // --- prep + CSR build ---
  k_prepw<<<24, 256, 0, stream>>>(W_in, W1, W2, wt);
  hipMemsetAsync(cnt, 0, (size_t)N * 4, stream);
  k_count<<<EB, 256, 0, stream>>>(edges, cnt, E);
  k_dinv <<<NB, 256, 0, stream>>>(cnt, dinv, N);
  k_scan1<<<NB, 256, 0, stream>>>(cnt, incl, bsum, N);
  k_scan2<<<1, 256, 0, stream>>>(bsum, NB);
  k_scan3<<<NB, 256, 0, stream>>>(incl, cnt, bsum, offs, curs, N, E);
  k_fill <<<EB, 256, 0, stream>>>(edges, curs, csr, E);

  int GB = (N + 63) / 64;
  int AB = (N + 3) / 4;

  // conv1: h1 = agg(x @ W_in) + b_in
  k_gemm<true> <<<GB, 256, 0, stream>>>(x, wt,             dinv, t, N);
  k_agg        <<<AB, 256, 0, stream>>>(t, offs, csr, dinv, b_in, h, N, 0);
  // conv2: h2 = relu(agg(h1 @ W1) + b1)
  k_gemm<false><<<GB, 256, 0, stream>>>(h, wt + 16384,     dinv, t, N);
  k_agg        <<<AB, 256, 0, stream>>>(t, offs, csr, dinv, b1, h, N, 1);
  // conv3: h3 = relu(agg(h2 @ W2) + b2)
  k_gemm<false><<<GB, 256, 0, stream>>>(h, wt + 2 * 16384, dinv, t, N);
  k_agg        <<<AB, 256, 0, stream>>>(t, offs, csr, dinv, b2, h, N, 1);

  // head + log_softmax (fused)
  k_head<<<GB, 256, 0, stream>>>(h, Wo, bo, out, N);
}

// Round 5
// 263.994 us; speedup vs baseline: 1.9955x; 1.0398x over previous
//
#include <hip/hip_runtime.h>
#include <hip/hip_bf16.h>
#include <math.h>

typedef unsigned int uint;
typedef unsigned short ushort;
typedef __attribute__((ext_vector_type(8))) short short8;   // 8 bf16 = 4 VGPRs
typedef __attribute__((ext_vector_type(4))) float f32x4;    // MFMA accumulator

__device__ __forceinline__ float bf_lo(uint u) { return __uint_as_float(u << 16); }
__device__ __forceinline__ float bf_hi(uint u) { return __uint_as_float(u & 0xffff0000u); }
__device__ __forceinline__ ushort f2bf(float f) {
  __hip_bfloat16 h = __float2bfloat16(f);   // RNE
  return *reinterpret_cast<ushort*>(&h);
}
__device__ __forceinline__ uint pack2(float a, float b) {
  return (uint)f2bf(a) | ((uint)f2bf(b) << 16);
}

// ===================== CSR build =====================
// XCD-partitioned: block b handles only dst in part (b&7). Atomics and csr
// line fills become XCD-local -> L2 merges them; dst re-reads served by L3.
__global__ __launch_bounds__(256) void k_count(
    const int* __restrict__ edges, int* __restrict__ cnt, int E, int npp, int nbp) {
  int part = blockIdx.x & 7;
  int lo = part * npp, hi = lo + npp;
  for (int e = (int)(blockIdx.x >> 3) * 256 + threadIdx.x; e < E; e += nbp * 256) {
    int d = edges[E + e];
    if (d >= lo && d < hi) atomicAdd(&cnt[d], 1);
  }
}

__global__ void k_dinv(const int* __restrict__ cnt, float* __restrict__ dinv, int n) {
  int i = blockIdx.x * 256 + threadIdx.x;
  if (i < n) dinv[i] = rsqrtf((float)cnt[i] + 1.0f);  // +1 = self loop
}

__global__ void k_scan1(const int* __restrict__ cnt, int* __restrict__ incl,
                        int* __restrict__ bsum, int n) {
  __shared__ int s[256];
  int tid = threadIdx.x;
  int gid = blockIdx.x * 256 + tid;
  int x = (gid < n) ? cnt[gid] : 0;
  s[tid] = x;
  __syncthreads();
  #pragma unroll
  for (int off = 1; off < 256; off <<= 1) {
    int t = (tid >= off) ? s[tid - off] : 0;
    __syncthreads();
    x += t; s[tid] = x;
    __syncthreads();
  }
  incl[gid] = x;
  if (tid == 255) bsum[blockIdx.x] = x;
}

__global__ void k_scan2(int* __restrict__ bsum, int nb) {
  __shared__ int s[256];
  int tid = threadIdx.x;
  int x = (tid < nb) ? bsum[tid] : 0;
  s[tid] = x;
  __syncthreads();
  #pragma unroll
  for (int off = 1; off < 256; off <<= 1) {
    int t = (tid >= off) ? s[tid - off] : 0;
    __syncthreads();
    x += t; s[tid] = x;
    __syncthreads();
  }
  if (tid < nb) bsum[tid] = x;
}

__global__ void k_scan3(const int* __restrict__ incl, const int* __restrict__ cnt,
                        const int* __restrict__ bsum, int* __restrict__ offs,
                        int* __restrict__ curs, int n, int E) {
  int gid = blockIdx.x * 256 + threadIdx.x;
  if (gid < n) {
    int base = (blockIdx.x > 0) ? bsum[blockIdx.x - 1] : 0;
    int v = incl[gid] - cnt[gid] + base;   // exclusive
    offs[gid] = v;
    curs[gid] = v;
  }
  if (gid == 0) offs[n] = E;
}

__global__ __launch_bounds__(256) void k_fill(
    const int* __restrict__ edges, int* __restrict__ curs,
    int* __restrict__ csr, int E, int npp, int nbp) {
  int part = blockIdx.x & 7;
  int lo = part * npp, hi = lo + npp;
  for (int e = (int)(blockIdx.x >> 3) * 256 + threadIdx.x; e < E; e += nbp * 256) {
    int d = edges[E + e];
    if (d >= lo && d < hi) {
      int s = edges[e];
      int pos = atomicAdd(&curs[d], 1);
      csr[pos] = s;
    }
  }
}

// ===================== W prep: fp32 [k][c] -> bf16 Wt [col][k] =====================
__global__ void k_prepw(const float* __restrict__ W_in, const float* __restrict__ W1,
                        const float* __restrict__ W2, ushort* __restrict__ Wt) {
  int b = blockIdx.x;
  const float* W = (b < 8) ? W_in : (b < 16) ? W1 : W2;
  ushort* dst = Wt + (size_t)(b >> 3) * 16384;
  int id = (b & 7) * 256 + threadIdx.x;    // 0..2047
  int col = id >> 4, kc = id & 15;
  const float* src = W + (size_t)(kc * 8) * 128 + col;
  uint4 pk;
  pk.x = pack2(src[0],       src[128]);
  pk.y = pack2(src[2 * 128], src[3 * 128]);
  pk.z = pack2(src[4 * 128], src[5 * 128]);
  pk.w = pack2(src[6 * 128], src[7 * 128]);
  ((uint4*)dst)[id] = pk;
}

// ===================== MFMA GEMM: T = bf16( (A @ W) * dinv[row] ) =====================
template <bool AF32>
__global__ __launch_bounds__(256) void k_gemm(
    const void* __restrict__ Ap, const ushort* __restrict__ Wt,
    const float* __restrict__ dinv, ushort* __restrict__ T, int n)
{
  __shared__ ushort sW[128 * 128];   // 32 KB: chunk (col,kc') at col*16+kc'
  int tid = threadIdx.x;
  {
    const uint4* Wt4 = (const uint4*)Wt;
    uint4* sW4 = (uint4*)sW;
    #pragma unroll
    for (int j = 0; j < 8; ++j) {
      int id = j * 256 + tid;
      int col = id >> 4, kc = id & 15;
      sW4[(col << 4) | (kc ^ (col & 7))] = Wt4[id];
    }
  }
  __syncthreads();

  int wid = tid >> 6, lane = tid & 63;
  int lr = lane & 15;    // A-row / B-col / D-col within fragment
  int lg = lane >> 4;    // k-group
  int rbase = blockIdx.x * 64 + wid * 16;
  int arow = rbase + lr;
  bool valid = arow < n;

  f32x4 acc[8];
  #pragma unroll
  for (int cf = 0; cf < 8; ++cf) acc[cf] = (f32x4){0.f, 0.f, 0.f, 0.f};

  #pragma unroll
  for (int ks = 0; ks < 4; ++ks) {
    short8 a = {};
    if (valid) {
      if constexpr (AF32) {
        const float4* Af = (const float4*)((const float*)Ap + (size_t)arow * 128) + (ks * 4 + lg) * 2;
        float4 u = Af[0], w = Af[1];
        union { uint4 u4; short8 s8; } cv;
        cv.u4.x = pack2(u.x, u.y); cv.u4.y = pack2(u.z, u.w);
        cv.u4.z = pack2(w.x, w.y); cv.u4.w = pack2(w.z, w.w);
        a = cv.s8;
      } else {
        a = ((const short8*)((const ushort*)Ap + (size_t)arow * 128))[ks * 4 + lg];
      }
    }
    int kc = (ks << 2) | lg;
    #pragma unroll
    for (int cf = 0; cf < 8; ++cf) {
      int col = (cf << 4) | lr;
      const short8* bp = (const short8*)sW + ((col << 4) | (kc ^ (lr & 7)));
      acc[cf] = __builtin_amdgcn_mfma_f32_16x16x32_bf16(a, *bp, acc[cf], 0, 0, 0);
    }
  }

  // D: col = cf*16 + lr, row = rbase + lg*4 + v
  #pragma unroll
  for (int v = 0; v < 4; ++v) {
    int row = rbase + (lg << 2) + v;
    if (row < n) {
      float s = dinv[row];
      ushort* dst = T + (size_t)row * 128 + lr;
      #pragma unroll
      for (int cf = 0; cf < 8; ++cf) dst[cf << 4] = f2bf(acc[cf][v] * s);
    }
  }
}

// ===================== sparse aggregate (bf16 in, bf16 out, fp32 accum) =====================
__global__ __launch_bounds__(256) void k_agg(
    const ushort* __restrict__ T, const int* __restrict__ offs,
    const int* __restrict__ csr, const float* __restrict__ dinv,
    const float* __restrict__ bias, ushort* __restrict__ H, int n, int relu)
{
  int u = (blockIdx.x << 2) + (threadIdx.x >> 6);
  if (u >= n) return;
  int lane = threadIdx.x & 63;
  const uint* Tu = (const uint*)T;
  uint su = Tu[(size_t)u * 64 + lane];   // self loop (row already * dinv[u])
  float ax = bf_lo(su), ay = bf_hi(su);
  int e0 = offs[u], e1 = offs[u + 1];
  int e = e0;
  for (; e + 4 <= e1; e += 4) {
    int s0 = csr[e], s1 = csr[e + 1], s2 = csr[e + 2], s3 = csr[e + 3];
    uint v0 = Tu[(size_t)s0 * 64 + lane];
    uint v1 = Tu[(size_t)s1 * 64 + lane];
    uint v2 = Tu[(size_t)s2 * 64 + lane];
    uint v3 = Tu[(size_t)s3 * 64 + lane];
    ax += (bf_lo(v0) + bf_lo(v1)) + (bf_lo(v2) + bf_lo(v3));
    ay += (bf_hi(v0) + bf_hi(v1)) + (bf_hi(v2) + bf_hi(v3));
  }
  for (; e < e1; ++e) {
    uint v = Tu[(size_t)csr[e] * 64 + lane];
    ax += bf_lo(v); ay += bf_hi(v);
  }
  float du = dinv[u];
  float2 b2 = *(const float2*)(bias + (lane << 1));
  float ox = fmaf(ax, du, b2.x);
  float oy = fmaf(ay, du, b2.y);
  if (relu) { ox = fmaxf(ox, 0.f); oy = fmaxf(oy, 0.f); }
  ((uint*)H)[(size_t)u * 64 + lane] = pack2(ox, oy);
}

// ===================== head: logits + fused log_softmax (bf16 H) =====================
__global__ __launch_bounds__(256) void k_head(
    const ushort* __restrict__ H, const float* __restrict__ Wo,
    const float* __restrict__ bo, float* __restrict__ out, int n)
{
  __shared__ float sWo[128 * 40];   // 20 KB
  __shared__ float sX[128 * 64];    // 32 KB, swizzled transpose
  int tid = threadIdx.x;
  int rbase = blockIdx.x * 64;

  {
    const float4* Wo4 = (const float4*)Wo;
    float4* sWo4 = (float4*)sWo;
    #pragma unroll
    for (int i = 0; i < 5; ++i) sWo4[i * 256 + tid] = Wo4[i * 256 + tid];
  }
  {
    const uint4* H4 = (const uint4*)H;
    #pragma unroll
    for (int j = 0; j < 4; ++j) {
      int id = j * 256 + tid;
      int r = id & 63, kc8 = id >> 6;   // kc8 = 0..15, 8 k-elems each
      int row = rbase + r;
      uint4 v = make_uint4(0u, 0u, 0u, 0u);
      if (row < n) v = H4[(size_t)row * 16 + kc8];
      float f[8] = {bf_lo(v.x), bf_hi(v.x), bf_lo(v.y), bf_hi(v.y),
                    bf_lo(v.z), bf_hi(v.z), bf_lo(v.w), bf_hi(v.w)};
      #pragma unroll
      for (int j2 = 0; j2 < 8; ++j2) {
        int k = kc8 * 8 + j2;
        int swz = ((k >> 2) & 7) << 2;
        sX[k * 64 + (r ^ swz)] = f[j2];
      }
    }
  }
  __syncthreads();

  int cg = tid & 7;    // 8 col groups x 5 cols
  int rg = tid >> 3;   // 32 row groups x 2 rows
  float bj[5];
  #pragma unroll
  for (int j = 0; j < 5; ++j) bj[j] = bo[cg * 5 + j];
  float acc[2][5];
  #pragma unroll
  for (int i = 0; i < 2; ++i)
    #pragma unroll
    for (int j = 0; j < 5; ++j) acc[i][j] = bj[j];

  #pragma unroll 4
  for (int k = 0; k < 128; ++k) {
    int swz = ((k >> 2) & 7) << 2;
    float2 xv = *(const float2*)(sX + k * 64 + ((rg << 1) ^ swz));
    const float* wr = sWo + k * 40 + cg * 5;
    float w0 = wr[0], w1 = wr[1], w2 = wr[2], w3 = wr[3], w4 = wr[4];
    acc[0][0] = fmaf(xv.x, w0, acc[0][0]);
    acc[0][1] = fmaf(xv.x, w1, acc[0][1]);
    acc[0][2] = fmaf(xv.x, w2, acc[0][2]);
    acc[0][3] = fmaf(xv.x, w3, acc[0][3]);
    acc[0][4] = fmaf(xv.x, w4, acc[0][4]);
    acc[1][0] = fmaf(xv.y, w0, acc[1][0]);
    acc[1][1] = fmaf(xv.y, w1, acc[1][1]);
    acc[1][2] = fmaf(xv.y, w2, acc[1][2]);
    acc[1][3] = fmaf(xv.y, w3, acc[1][3]);
    acc[1][4] = fmaf(xv.y, w4, acc[1][4]);
  }

  #pragma unroll
  for (int i = 0; i < 2; ++i) {
    int row = rbase + (rg << 1) + i;
    float m = acc[i][0];
    m = fmaxf(m, acc[i][1]); m = fmaxf(m, acc[i][2]);
    m = fmaxf(m, acc[i][3]); m = fmaxf(m, acc[i][4]);
    m = fmaxf(m, __shfl_xor(m, 1));
    m = fmaxf(m, __shfl_xor(m, 2));
    m = fmaxf(m, __shfl_xor(m, 4));
    float s = 0.f;
    #pragma unroll
    for (int j = 0; j < 5; ++j) s += __expf(acc[i][j] - m);
    s += __shfl_xor(s, 1);
    s += __shfl_xor(s, 2);
    s += __shfl_xor(s, 4);
    float ls = m + __logf(s);
    if (row < n) {
      float* dst = out + (size_t)row * 40 + cg * 5;
      #pragma unroll
      for (int j = 0; j < 5; ++j) dst[j] = acc[i][j] - ls;
    }
  }
}

// ===================== launch =====================
extern "C" void kernel_launch(void* const* d_in, const int* in_sizes, int n_in,
                              void* d_out, int out_size, void* d_ws, size_t ws_size,
                              hipStream_t stream) {
  const float* x    = (const float*)d_in[0];
  const int*   edges= (const int*)d_in[1];
  const float* W_in = (const float*)d_in[2];
  const float* b_in = (const float*)d_in[3];
  const float* W1   = (const float*)d_in[4];
  const float* b1   = (const float*)d_in[5];
  const float* W2   = (const float*)d_in[6];
  const float* b2   = (const float*)d_in[7];
  const float* Wo   = (const float*)d_in[8];
  const float* bo   = (const float*)d_in[9];
  float* out = (float*)d_out;

  int N = in_sizes[0] / 128;
  int E = in_sizes[1] / 2;
  int NB = (N + 255) / 256;

  char* p = (char*)d_ws;
  auto alloc = [&](size_t bytes) {
    char* r = p; p += (bytes + 255) & ~(size_t)255; return r;
  };
  ushort* t   = (ushort*)alloc((size_t)N * 128 * 2);
  ushort* h   = (ushort*)alloc((size_t)N * 128 * 2);
  ushort* wt  = (ushort*)alloc(3 * 16384 * 2);
  int*   cnt  = (int*)  alloc((size_t)N * 4);
  float* dinv = (float*)alloc((size_t)N * 4);
  int*   incl = (int*)  alloc((size_t)NB * 256 * 4);
  int*   bsum = (int*)  alloc(256 * 4);
  int*   offs = (int*)  alloc((size_t)(N + 1) * 4);
  int*   curs = (int*)  alloc((size_t)N * 4);
  int*   csr  = (int*)  alloc((size_t)E * 4);
  (void)ws_size; (void)n_in; (void)out_size;

  // --- prep + CSR build (XCD-partitioned count/fill) ---
  int NPP = (N + 7) / 8;       // nodes per partition
  int NBP = 512;               // blocks per partition
  k_prepw<<<24, 256, 0, stream>>>(W_in, W1, W2, wt);
  hipMemsetAsync(cnt, 0, (size_t)N * 4, stream);
  k_count<<<NBP * 8, 256, 0, stream>>>(edges, cnt, E, NPP, NBP);
  k_dinv <<<NB, 256, 0, stream>>>(cnt, dinv, N);
  k_scan1<<<NB, 256, 0, stream>>>(cnt, incl, bsum, N);
  k_scan2<<<1, 256, 0, stream>>>(bsum, NB);
  k_scan3<<<NB, 256, 0, stream>>>(incl, cnt, bsum, offs, curs, N, E);
  k_fill <<<NBP * 8, 256, 0, stream>>>(edges, curs, csr, E, NPP, NBP);

  int GB = (N + 63) / 64;
  int AB = (N + 3) / 4;

  // conv1: h1 = agg(x @ W_in) + b_in
  k_gemm<true> <<<GB, 256, 0, stream>>>(x, wt,             dinv, t, N);
  k_agg        <<<AB, 256, 0, stream>>>(t, offs, csr, dinv, b_in, h, N, 0);
  // conv2: h2 = relu(agg(h1 @ W1) + b1)
  k_gemm<false><<<GB, 256, 0, stream>>>(h, wt + 16384,     dinv, t, N);
  k_agg        <<<AB, 256, 0, stream>>>(t, offs, csr, dinv, b1, h, N, 1);
  // conv3: h3 = relu(agg(h2 @ W2) + b2)
  k_gemm<false><<<GB, 256, 0, stream>>>(h, wt + 2 * 16384, dinv, t, N);
  k_agg        <<<AB, 256, 0, stream>>>(t, offs, csr, dinv, b2, h, N, 1);

  // head + log_softmax (fused)
  k_head<<<GB, 256, 0, stream>>>(h, Wo, bo, out, N);
}